// Round 6
// baseline (474.942 us; speedup 1.0000x reference)
//
#include <hip/hip_runtime.h>
#include <stdint.h>

// Problem constants (from reference): B,T,X,E,H,L = 4096,32,256,32,512,2
#define B_SZ 4096
#define T_SZ 32
#define X_SZ 256
#define E_SZ 32
#define H_SZ 512
#define BM   64      // batch rows per block
#define AROW 1040    // A-tile LDS row stride bytes (512 bf16 + 16B pad)
#define D_SZ 288     // T+X

typedef __attribute__((ext_vector_type(8)))  short short8;   // 8 bf16 = 4 VGPR
typedef __attribute__((ext_vector_type(16))) float floatx16; // 32x32 acc

__device__ __forceinline__ unsigned short f2bf(float f) {
  unsigned u = __float_as_uint(f);
  u += 0x7fffu + ((u >> 16) & 1u);          // RNE
  return (unsigned short)(u >> 16);
}
__device__ __forceinline__ unsigned pk2(float a, float b) {
  return (unsigned)f2bf(a) | ((unsigned)f2bf(b) << 16);
}

// ---------------------------------------------------------------------------
// Prep v6: coalesced, conflict-free; emits 32x32x16-MFMA B-fragment order.
// Chunk = (matrix, 32-k rows) = 512n x 32k = 2048 16B units. Unit u:
//   nt=u>>7 (n-tile of 32), s=(u>>6)&1 (k-half of 16), l=u&63
//   n = nt*32 + (l&31), k0 = s*16 + (l>>5)*8; unit = 8 bf16 along k at col n.
// Blocks [0,1312): weights (bid&7 = XCD owning experts 4x..4x+3; expert
// 4x+3 first, 4x+0 last). c<9: layer-1 cat (masked W1t rows), else hidden.
// Blocks [1312,1376): tx[r] = bf16([theta[r] | x[r]]).
// LPITCH=526: 8-row stride = 2104 dw = +24 banks -> gather groups disjoint.
// ---------------------------------------------------------------------------
#define LPITCH 526

__global__ __launch_bounds__(256) void prep6_kernel(
    const float* __restrict__ W1t, const float* __restrict__ W1x,
    const int* __restrict__ masks, const float* __restrict__ Wh,
    const float* __restrict__ theta, const float* __restrict__ x,
    uint4* __restrict__ wcat, uint4* __restrict__ whf,
    unsigned short* __restrict__ tx) {
  const int bid = blockIdx.x, t = threadIdx.x;
  if (bid >= 1312) {                      // ---- activation conversion ----
    int g = bid - 1312;
    int r = g * 64 + (t >> 2), c = t & 3; // 4 threads per row
    {
      float4 a = *(const float4*)(theta + (size_t)r * T_SZ + c * 8);
      float4 b = *(const float4*)(theta + (size_t)r * T_SZ + c * 8 + 4);
      *(uint4*)(tx + (size_t)r * D_SZ + c * 8) =
          make_uint4(pk2(a.x, a.y), pk2(a.z, a.w), pk2(b.x, b.y), pk2(b.z, b.w));
    }
#pragma unroll
    for (int j = 0; j < 8; ++j) {
      float4 a = *(const float4*)(x + (size_t)r * X_SZ + c * 64 + j * 8);
      float4 b = *(const float4*)(x + (size_t)r * X_SZ + c * 64 + j * 8 + 4);
      *(uint4*)(tx + (size_t)r * D_SZ + T_SZ + c * 64 + j * 8) =
          make_uint4(pk2(a.x, a.y), pk2(a.z, a.w), pk2(b.x, b.y), pk2(b.z, b.w));
    }
    return;
  }
  __shared__ unsigned short lds[32 * LPITCH];
  const int xcd = bid & 7, j = bid >> 3;
  const int q41 = j / 41;
  const int c   = j - q41 * 41;           // chunk within expert, 0..40
  const int e   = xcd * 4 + (3 - q41);
  float4 v[16];
  if (c < 9) {
#pragma unroll
    for (int p = 0; p < 16; ++p) {
      int f  = p * 256 + t;
      int kk = f >> 7, n = (f & 127) * 4;
      int k  = c * 32 + kk;
      if (k < T_SZ) {
        v[p] = *(const float4*)(W1t + ((size_t)e * T_SZ + k) * H_SZ + n);
        float m = (float)masks[e * T_SZ + k];
        v[p].x *= m; v[p].y *= m; v[p].z *= m; v[p].w *= m;
      } else {
        v[p] = *(const float4*)(W1x + ((size_t)e * X_SZ + (k - T_SZ)) * H_SZ + n);
      }
    }
  } else {
    int h = c - 9, le = h >> 4, kt = h & 15;
    const float* base = Wh + (size_t)(le * E_SZ + e) * H_SZ * H_SZ +
                        (size_t)kt * 32 * H_SZ;
#pragma unroll
    for (int p = 0; p < 16; ++p) {
      int f  = p * 256 + t;
      int kk = f >> 7, n = (f & 127) * 4;
      v[p] = *(const float4*)(base + (size_t)kk * H_SZ + n);
    }
  }
  unsigned* lds32 = (unsigned*)lds;
#pragma unroll
  for (int p = 0; p < 16; ++p) {
    int f  = p * 256 + t;
    int kk = f >> 7, n = (f & 127) * 4;
    int di = (kk * LPITCH + n) >> 1;
    lds32[di]     = pk2(v[p].x, v[p].y);
    lds32[di + 1] = pk2(v[p].z, v[p].w);
  }
  __syncthreads();
  uint4* dst = (c < 9)
                   ? (wcat + ((size_t)e * 9 + c) * 2048)
                   : (whf + ((size_t)(((c - 9) >> 4) * E_SZ + e) * 16 +
                             ((c - 9) & 15)) * 2048);
#pragma unroll 2
  for (int p = 0; p < 8; ++p) {
    int u  = p * 256 + t;
    int nt = u >> 7, s = (u >> 6) & 1, l = u & 63;
    int n  = nt * 32 + (l & 31);
    int k0 = s * 16 + (l >> 5) * 8;
    unsigned d[4];
#pragma unroll
    for (int jj = 0; jj < 4; ++jj) {
      unsigned lo = lds[(k0 + 2 * jj)     * LPITCH + n];
      unsigned hi = lds[(k0 + 2 * jj + 1) * LPITCH + n];
      d[jj] = lo | (hi << 16);
    }
    dst[u] = make_uint4(d[0], d[1], d[2], d[3]);
  }
}

// ---------------------------------------------------------------------------
// GEMM over NKT K-chunks of 32 using v_mfma_f32_32x32x16_bf16.
// A frag: m = l&31, k = kstep*16 + (l>>5)*8 + j  (gfx950 2xK doubling of the
// verified CDNA 32x32 pattern; 16x16 analog HW-verified by rounds 1-5).
// B frag identical with n = l&31. acc[mt][j] C-layout (m74/m101-verified):
// col = l&31, row = (reg&3) + 8*(reg>>2) + 4*(l>>5).
// B prefetched one kt ahead from global; A single-buffered from LDS.
// ---------------------------------------------------------------------------
template <int NKT>
__device__ __forceinline__ void gemm32(const char* smA, const short8* wp,
                                       int l, floatx16 (&acc)[2][2]) {
  const int l31 = l & 31, lh = l >> 5;
#pragma unroll
  for (int mt = 0; mt < 2; ++mt)
#pragma unroll
    for (int j = 0; j < 2; ++j) acc[mt][j] = (floatx16)(0.f);
  short8 b[2][4];
#pragma unroll
  for (int i = 0; i < 4; ++i) b[0][i] = wp[i * 64];
#pragma unroll
  for (int kt = 0; kt < NKT; ++kt) {
    const int cur = kt & 1, nxt = cur ^ 1;
    const int kn  = (kt + 1 < NKT) ? kt + 1 : kt;
#pragma unroll
    for (int i = 0; i < 4; ++i) b[nxt][i] = wp[(size_t)kn * 2048 + i * 64];
    short8 a[2][2];
#pragma unroll
    for (int mt = 0; mt < 2; ++mt)
#pragma unroll
      for (int s = 0; s < 2; ++s)
        a[mt][s] = *(const short8*)(smA + (mt * 32 + l31) * AROW + kt * 64 +
                                    s * 32 + lh * 16);
#pragma unroll
    for (int mt = 0; mt < 2; ++mt)
#pragma unroll
      for (int j = 0; j < 2; ++j)
#pragma unroll
        for (int s = 0; s < 2; ++s)
          acc[mt][j] = __builtin_amdgcn_mfma_f32_32x32x16_bf16(
              a[mt][s], b[cur][j * 2 + s], acc[mt][j], 0, 0, 0);
  }
}

// ---------------------------------------------------------------------------
// Fused MLP: grid 2048 = (64 m-tiles x 8 XCDs) x 4 expert-groups.
// e = (bid&7)*4 + (bid>>9) (e-outer for soft L2 phasing), m0 = ((bid>>3)&63)*64.
// 8 waves; wave w owns cols [64w,64w+64) as two 32-wide n-tiles.
// ---------------------------------------------------------------------------
__global__ __launch_bounds__(512, 4) void mlp_kernel(
    const unsigned short* __restrict__ tx,
    const short8* __restrict__ wcat, const short8* __restrict__ whf,
    const float* __restrict__ b1, const float* __restrict__ a1,
    const float* __restrict__ bh, const float* __restrict__ ah,
    const float* __restrict__ Wo, const float* __restrict__ bo,
    float* __restrict__ out) {
  __shared__ __align__(16) char smA[BM * AROW];   // 66560 B
  const int tid = threadIdx.x;
  const int bid = blockIdx.x;
  const int e   = (bid & 7) * 4 + (bid >> 9);
  const int m0  = ((bid >> 3) & 63) * BM;
  const int w   = tid >> 6, l = tid & 63, l31 = l & 31, lh = l >> 5;

  // ---- stage A0 = bf16 [theta|x] rows (pre-converted by prep) ----
  {
    int r = tid >> 3, c = tid & 7;
    const unsigned short* src = tx + (size_t)(m0 + r) * D_SZ;
#pragma unroll
    for (int q = 0; q < 9; ++q)
      *(uint2*)(smA + r * AROW + 8 * (c + 8 * q)) =
          *(const uint2*)(src + 4 * (c + 8 * q));
  }
  __syncthreads();

  floatx16 acc[2][2];

  // bias + PReLU + bf16 pair-pack (shfl_xor 1) + write back into A buffer.
  // Even lanes store regs 0..7, odd lanes regs 8..15 (all rows covered).
  auto epi_store = [&](const float* bias, const float* slope) {
    float bb[2], aa[2];
#pragma unroll
    for (int j = 0; j < 2; ++j) {
      int col = w * 64 + j * 32 + l31;
      bb[j] = bias[col];
      aa[j] = slope[col];
    }
    __syncthreads();   // everyone done READING A before we overwrite
#pragma unroll
    for (int mt = 0; mt < 2; ++mt) {
#pragma unroll
      for (int j = 0; j < 2; ++j) {
        unsigned dw[16];
#pragma unroll
        for (int r = 0; r < 16; ++r) {
          float v = acc[mt][j][r] + bb[j];
          v = v >= 0.f ? v : aa[j] * v;
          float o  = __shfl_xor(v, 1, 64);
          float lo = (l & 1) ? o : v;
          float hi = (l & 1) ? v : o;
          dw[r] = pk2(lo, hi);
        }
        int col2  = w * 64 + j * 32 + (l31 & ~1);
        int rbase = (l & 1) * 8;
#pragma unroll
        for (int rr = 0; rr < 8; ++rr) {
          int r   = rbase + rr;
          int row = mt * 32 + (r & 3) + 8 * (r >> 2) + 4 * lh;
          *(unsigned*)(smA + row * AROW + col2 * 2) = dw[r];
        }
      }
    }
    __syncthreads();
  };

  const int woff = w * 256 + l;
  // ---- layer 1: K = 288 (9 chunks) ----
  gemm32<9>(smA, wcat + (size_t)e * 9 * 2048 + woff, l, acc);
  epi_store(b1 + (size_t)e * H_SZ, a1 + (size_t)e * H_SZ);
  // ---- hidden layer 0: K = 512 (16 chunks) ----
  gemm32<16>(smA, whf + (size_t)e * 16 * 2048 + woff, l, acc);
  epi_store(bh + (size_t)e * H_SZ, ah + (size_t)e * H_SZ);
  // ---- hidden layer 1 ----
  gemm32<16>(smA, whf + (size_t)(E_SZ + e) * 16 * 2048 + woff, l, acc);
  epi_store(bh + (size_t)(E_SZ + e) * H_SZ, ah + (size_t)(E_SZ + e) * H_SZ);
  // ---- output dot: act (bf16 in smA) . Wo[e] ----
  {
    int row = tid >> 3, c8 = tid & 7;     // 8 threads per batch row
    float s = 0.f;
    const float* wo = Wo + (size_t)e * H_SZ;
#pragma unroll
    for (int j = 0; j < 8; ++j) {
      int colb = c8 * 16 + j * 128;       // byte offset; 8 cols per chunk
      short8 av = *(const short8*)(smA + row * AROW + colb);
      int col   = c8 * 8 + j * 64;
      float4 w0 = *(const float4*)(wo + col);
      float4 w1 = *(const float4*)(wo + col + 4);
      float wv[8] = {w0.x, w0.y, w0.z, w0.w, w1.x, w1.y, w1.z, w1.w};
#pragma unroll
      for (int k = 0; k < 8; ++k) {
        float av_f = __uint_as_float(((unsigned)(unsigned short)av[k]) << 16);
        s += av_f * wv[k];
      }
    }
#pragma unroll
    for (int d = 1; d < 8; d <<= 1) s += __shfl_xor(s, d, 64);
    if (c8 == 0) out[(size_t)(m0 + row) * E_SZ + e] = s + bo[e];
  }
}

// ---------------------------------------------------------------------------
extern "C" void kernel_launch(void* const* d_in, const int* in_sizes, int n_in,
                              void* d_out, int out_size, void* d_ws, size_t ws_size,
                              hipStream_t stream) {
  const float* theta = (const float*)d_in[0];
  const float* x     = (const float*)d_in[1];
  const int*   masks = (const int*)d_in[2];
  const float* W1t   = (const float*)d_in[3];
  const float* W1x   = (const float*)d_in[4];
  const float* b1    = (const float*)d_in[5];
  const float* a1    = (const float*)d_in[6];
  const float* Wh    = (const float*)d_in[7];
  const float* bh    = (const float*)d_in[8];
  const float* ah    = (const float*)d_in[9];
  const float* Wo    = (const float*)d_in[10];
  const float* bo    = (const float*)d_in[11];
  float* out = (float*)d_out;

  // ws layout: [0, 9.4MB) layer-1 frags; [+33.5MB) hidden frags; [+2.4MB) tx.
  uint4* wcat = (uint4*)d_ws;
  uint4* whf  = (uint4*)((char*)d_ws + (size_t)E_SZ * 9 * 2048 * 16);
  unsigned short* tx =
      (unsigned short*)((char*)d_ws + (size_t)E_SZ * 9 * 2048 * 16 +
                        (size_t)2 * E_SZ * 16 * 2048 * 16);

  prep6_kernel<<<1376, 256, 0, stream>>>(W1t, W1x, masks, Wh, theta, x,
                                         wcat, whf, tx);
  mlp_kernel<<<2048, 512, 0, stream>>>(tx, (const short8*)wcat,
                                       (const short8*)whf, b1, a1, bh, ah, Wo,
                                       bo, out);
}